// Round 4
// baseline (129.994 us; speedup 1.0000x reference)
//
#include <hip/hip_runtime.h>
#include <hip/hip_fp16.h>

// NNUE (HalfKA) fused forward pass for MI355X.
// Round 4: int8 table + explicit 16-deep load staging with scalar (SGPR)
// row indices -> ~16 independent row loads in flight per wave.

#define FEATS 32
#define FTO   1024
#define HH    512
#define FT_ELEMS (22528ULL * 1024ULL)      // int8 bytes = 23,068,672
#define QSCALE   (6.0f / 127.0f)

__device__ __forceinline__ float clip127(float x) {
    return fminf(fmaxf(x, 0.0f), 127.0f);
}

// ---------------- fp32 -> biased int8 quantize ----------------
__global__ __launch_bounds__(256) void quant_f32_u8(const float4* __restrict__ src,
                                                    uint4* __restrict__ dst,
                                                    unsigned n16) {
    unsigned i = blockIdx.x * 256 + threadIdx.x;
    const unsigned stride = gridDim.x * 256;
    const float inv = 127.0f / 6.0f;
    for (; i < n16; i += stride) {
        unsigned w[4];
        #pragma unroll
        for (int j = 0; j < 4; ++j) {
            const float4 v = src[4 * (size_t)i + j];
            const unsigned q0 = (unsigned)(__float2int_rn(fminf(fmaxf(v.x * inv, -127.f), 127.f)) + 128);
            const unsigned q1 = (unsigned)(__float2int_rn(fminf(fmaxf(v.y * inv, -127.f), 127.f)) + 128);
            const unsigned q2 = (unsigned)(__float2int_rn(fminf(fmaxf(v.z * inv, -127.f), 127.f)) + 128);
            const unsigned q3 = (unsigned)(__float2int_rn(fminf(fmaxf(v.w * inv, -127.f), 127.f)) + 128);
            w[j] = q0 | (q1 << 8) | (q2 << 16) | (q3 << 24);
        }
        dst[i] = make_uint4(w[0], w[1], w[2], w[3]);
    }
}

// ---------------- main fused kernel, int8 table ----------------
// Wave roles: wave = tid>>6; bag = wave>>1 (0=w,1=b); half = wave&1.
// Each wave gathers 16 full rows (64 lanes x 16B = 1024B = one int8 row).
// Lane owns cols [16*lane, 16*lane+16), accumulated as 8 packed-u16 words.
__global__ __launch_bounds__(256, 4) void nnue_fwd_q8(
    const int*   __restrict__ w_feats,
    const int*   __restrict__ b_feats,
    const int*   __restrict__ stm,
    const int*   __restrict__ bucket,
    const uint4* __restrict__ tbl,       // int8 table, 64 x uint4 per row
    const float* __restrict__ ft_bias,
    const float* __restrict__ psqt_w,
    const float* __restrict__ fc0_w,
    const float* __restrict__ fc0_b,
    const float* __restrict__ fc1_w,
    const float* __restrict__ fc1_b,
    const float* __restrict__ fc2_w,
    const float* __restrict__ fc2_b,
    float*       __restrict__ out)
{
    const int b    = blockIdx.x;
    const int tid  = threadIdx.x;
    const int lane = tid & 63;
    const int wv   = tid >> 6;

    __shared__ unsigned pk[2][2][512];          // [dst][half][word] packed u16 pairs
    __shared__ float    s_part[4][16];
    __shared__ float    s_o0[16];
    __shared__ float    s_psqt[16];

    // wave-uniform role (readfirstlane so index loads go scalar)
    const int wvu  = __builtin_amdgcn_readfirstlane(wv);
    const int bag  = wvu >> 1;
    const int half = wvu & 1;

    // ---- scalar row indices for this wave's 16 rows ----
    const int* __restrict__ g = bag ? b_feats : w_feats;
    int idx[16];
    #pragma unroll
    for (int k = 0; k < 16; ++k)
        idx[k] = g[b * FEATS + half * 16 + k];

    // ---- issue all 16 row loads, then decode ----
    uint4 buf[16];
    #pragma unroll
    for (int k = 0; k < 16; ++k)
        buf[k] = tbl[(size_t)idx[k] * 64 + lane];

    unsigned pa[8] = {0, 0, 0, 0, 0, 0, 0, 0};
    #pragma unroll
    for (int k = 0; k < 16; ++k) {
        const uint4 v = buf[k];
        pa[0] += __builtin_amdgcn_perm(v.x, v.x, 0x0C010C00u);
        pa[1] += __builtin_amdgcn_perm(v.x, v.x, 0x0C030C02u);
        pa[2] += __builtin_amdgcn_perm(v.y, v.y, 0x0C010C00u);
        pa[3] += __builtin_amdgcn_perm(v.y, v.y, 0x0C030C02u);
        pa[4] += __builtin_amdgcn_perm(v.z, v.z, 0x0C010C00u);
        pa[5] += __builtin_amdgcn_perm(v.z, v.z, 0x0C030C02u);
        pa[6] += __builtin_amdgcn_perm(v.w, v.w, 0x0C010C00u);
        pa[7] += __builtin_amdgcn_perm(v.w, v.w, 0x0C030C02u);
    }

    const int st  = stm[b];
    const int dst = bag ? (1 - st) : st;
    {
        unsigned* pw = &pk[dst][half][lane * 8];
        reinterpret_cast<uint4*>(pw)[0] = make_uint4(pa[0], pa[1], pa[2], pa[3]);
        reinterpret_cast<uint4*>(pw)[1] = make_uint4(pa[4], pa[5], pa[6], pa[7]);
    }

    // ---- psqt gather-sum (tiny fp32 table; indices straight from global) ----
    if (tid < 16) {
        const int* ff = ((tid < 8) ? w_feats : b_feats) + b * FEATS;
        const int  j  = tid & 7;
        float s = 0.0f;
        #pragma unroll 4
        for (int k = 0; k < FEATS; ++k) s += psqt_w[(size_t)ff[k] * 8 + j];
        s_psqt[tid] = s;
    }
    __syncthreads();

    // ---- combine halves, decode, pairwise clip-mult ----
    const int d   = (tid < 128) ? 0 : 1;
    const int tau = tid & 127;

    const uint2 l0 = *reinterpret_cast<const uint2*>(&pk[d][0][2 * tau]);
    const uint2 l1 = *reinterpret_cast<const uint2*>(&pk[d][1][2 * tau]);
    const uint2 h0 = *reinterpret_cast<const uint2*>(&pk[d][0][2 * tau + 256]);
    const uint2 h1 = *reinterpret_cast<const uint2*>(&pk[d][1][2 * tau + 256]);
    const unsigned wl0 = l0.x + l1.x, wl1 = l0.y + l1.y;   // u16 lanes: cols cb..cb+3
    const unsigned wh0 = h0.x + h1.x, wh1 = h0.y + h1.y;   // cols cb+512..cb+515

    const float4 fb_lo = reinterpret_cast<const float4*>(ft_bias)[tau];
    const float4 fb_hi = reinterpret_cast<const float4*>(ft_bias)[tau + 128];
    const float  qs    = QSCALE;
    const float  qoff  = -4096.0f * QSCALE;   // 32 rows * 128 bias

    float4 alo, ahi;
    alo.x = (float)(wl0 & 0xFFFFu) * qs + (fb_lo.x + qoff);
    alo.y = (float)(wl0 >> 16)     * qs + (fb_lo.y + qoff);
    alo.z = (float)(wl1 & 0xFFFFu) * qs + (fb_lo.z + qoff);
    alo.w = (float)(wl1 >> 16)     * qs + (fb_lo.w + qoff);
    ahi.x = (float)(wh0 & 0xFFFFu) * qs + (fb_hi.x + qoff);
    ahi.y = (float)(wh0 >> 16)     * qs + (fb_hi.y + qoff);
    ahi.z = (float)(wh1 & 0xFFFFu) * qs + (fb_hi.z + qoff);
    ahi.w = (float)(wh1 >> 16)     * qs + (fb_hi.w + qoff);

    float4 ft4;
    ft4.x = clip127(alo.x) * clip127(ahi.x) * (1.0f/128.0f);
    ft4.y = clip127(alo.y) * clip127(ahi.y) * (1.0f/128.0f);
    ft4.z = clip127(alo.z) * clip127(ahi.z) * (1.0f/128.0f);
    ft4.w = clip127(alo.w) * clip127(ahi.w) * (1.0f/128.0f);

    // ---- fc0: 16 outputs, dot over 1024 ----
    const int bk = bucket[b];
    const float4* __restrict__ w0 =
        reinterpret_cast<const float4*>(fc0_w + (size_t)bk * 16 * FTO);
    float p[16];
    #pragma unroll
    for (int o = 0; o < 16; ++o) {
        const float4 w = w0[o * 256 + tid];
        p[o] = ft4.x * w.x + ft4.y * w.y + ft4.z * w.z + ft4.w * w.w;
    }
    #pragma unroll
    for (int o = 0; o < 16; ++o) {
        float v = p[o];
        v += __shfl_down(v, 32);
        v += __shfl_down(v, 16);
        v += __shfl_down(v, 8);
        v += __shfl_down(v, 4);
        v += __shfl_down(v, 2);
        v += __shfl_down(v, 1);
        if (lane == 0) s_part[wv][o] = v;
    }
    __syncthreads();
    if (tid < 16) {
        s_o0[tid] = s_part[0][tid] + s_part[1][tid] + s_part[2][tid] + s_part[3][tid]
                  + fc0_b[bk * 16 + tid];
    }
    __syncthreads();

    // ---- tail: fc1 (32x32), fc2 (1x32), skip, psqt ----
    if (tid < 32) {
        const float* __restrict__ w1 = fc1_w + ((size_t)bk * 32 + tid) * 32;
        float o1 = fc1_b[bk * 32 + tid];
        #pragma unroll
        for (int i = 0; i < 15; ++i) {
            const float o0i = s_o0[i];
            const float sq  = clip127(o0i * o0i * (1.0f/524288.0f));
            const float rl  = clip127(o0i * (1.0f/64.0f));
            o1 += sq * w1[i] + rl * w1[15 + i];
        }
        const float ac1 = clip127(o1 * (1.0f/64.0f));
        float v = ac1 * fc2_w[bk * 32 + tid];
        v += __shfl_down(v, 16);
        v += __shfl_down(v, 8);
        v += __shfl_down(v, 4);
        v += __shfl_down(v, 2);
        v += __shfl_down(v, 1);
        if (tid == 0) {
            const float scalar = v + fc2_b[bk];
            const float skip   = s_o0[15] * (9600.0f / 8128.0f);
            const float p_stm  = st ? s_psqt[8 + bk] : s_psqt[bk];
            const float p_opp  = st ? s_psqt[bk]     : s_psqt[8 + bk];
            const float psqt   = (p_stm - p_opp) * 0.5f;
            out[b] = (psqt + scalar + skip) * (1.0f/16.0f);
        }
    }
}

// ---------------- fp32 fallback (round-1 kernel) ----------------
__global__ __launch_bounds__(256) void nnue_fwd_f32(
    const int*   __restrict__ w_feats,
    const int*   __restrict__ b_feats,
    const int*   __restrict__ stm,
    const int*   __restrict__ bucket,
    const float* __restrict__ ft_w,
    const float* __restrict__ ft_bias,
    const float* __restrict__ psqt_w,
    const float* __restrict__ fc0_w,
    const float* __restrict__ fc0_b,
    const float* __restrict__ fc1_w,
    const float* __restrict__ fc1_b,
    const float* __restrict__ fc2_w,
    const float* __restrict__ fc2_b,
    float*       __restrict__ out)
{
    const int b   = blockIdx.x;
    const int tid = threadIdx.x;

    __shared__ int   sfw[FEATS];
    __shared__ int   sfb[FEATS];
    __shared__ float s_acc[2][FTO];
    __shared__ float s_part[4][16];
    __shared__ float s_o0[16];
    __shared__ float s_psqt[16];

    if (tid < FEATS)          sfw[tid]         = w_feats[b * FEATS + tid];
    else if (tid < 2 * FEATS) sfb[tid - FEATS] = b_feats[b * FEATS + (tid - FEATS)];
    __syncthreads();

    const float4* __restrict__ ftw4 = reinterpret_cast<const float4*>(ft_w);
    const float4 bias4 = reinterpret_cast<const float4*>(ft_bias)[tid];
    float4 aw = bias4, ab = bias4;

    #pragma unroll 8
    for (int k = 0; k < FEATS; ++k) {
        const float4 rw = ftw4[(size_t)sfw[k] * 256 + tid];
        const float4 rb = ftw4[(size_t)sfb[k] * 256 + tid];
        aw.x += rw.x; aw.y += rw.y; aw.z += rw.z; aw.w += rw.w;
        ab.x += rb.x; ab.y += rb.y; ab.z += rb.z; ab.w += rb.w;
    }

    if (tid < 16) {
        const int* f = (tid < 8) ? sfw : sfb;
        const int  j = tid & 7;
        float s = 0.0f;
        #pragma unroll 4
        for (int k = 0; k < FEATS; ++k) s += psqt_w[(size_t)f[k] * 8 + j];
        s_psqt[tid] = s;
    }

    const int st = stm[b];
    const float4 astm = st ? ab : aw;
    const float4 aopp = st ? aw : ab;

    reinterpret_cast<float4*>(&s_acc[0][0])[tid] = astm;
    reinterpret_cast<float4*>(&s_acc[1][0])[tid] = aopp;
    __syncthreads();

    float4 ft4;
    if (tid < 128) {
        const float4 lo = astm;
        const float4 hi = *reinterpret_cast<const float4*>(&s_acc[0][HH + tid * 4]);
        ft4.x = clip127(lo.x) * clip127(hi.x) * (1.0f/128.0f);
        ft4.y = clip127(lo.y) * clip127(hi.y) * (1.0f/128.0f);
        ft4.z = clip127(lo.z) * clip127(hi.z) * (1.0f/128.0f);
        ft4.w = clip127(lo.w) * clip127(hi.w) * (1.0f/128.0f);
    } else {
        const float4 lo = *reinterpret_cast<const float4*>(&s_acc[1][(tid - 128) * 4]);
        const float4 hi = aopp;
        ft4.x = clip127(lo.x) * clip127(hi.x) * (1.0f/128.0f);
        ft4.y = clip127(lo.y) * clip127(hi.y) * (1.0f/128.0f);
        ft4.z = clip127(lo.z) * clip127(hi.z) * (1.0f/128.0f);
        ft4.w = clip127(lo.w) * clip127(hi.w) * (1.0f/128.0f);
    }

    const int bk = bucket[b];
    const float4* __restrict__ w0 =
        reinterpret_cast<const float4*>(fc0_w + (size_t)bk * 16 * FTO);
    float p[16];
    #pragma unroll
    for (int o = 0; o < 16; ++o) {
        const float4 w = w0[o * 256 + tid];
        p[o] = ft4.x * w.x + ft4.y * w.y + ft4.z * w.z + ft4.w * w.w;
    }
    const int lane = tid & 63;
    const int wv   = tid >> 6;
    #pragma unroll
    for (int o = 0; o < 16; ++o) {
        float v = p[o];
        v += __shfl_down(v, 32);
        v += __shfl_down(v, 16);
        v += __shfl_down(v, 8);
        v += __shfl_down(v, 4);
        v += __shfl_down(v, 2);
        v += __shfl_down(v, 1);
        if (lane == 0) s_part[wv][o] = v;
    }
    __syncthreads();
    if (tid < 16) {
        s_o0[tid] = s_part[0][tid] + s_part[1][tid] + s_part[2][tid] + s_part[3][tid]
                  + fc0_b[bk * 16 + tid];
    }
    __syncthreads();

    if (tid < 32) {
        const float* __restrict__ w1 = fc1_w + ((size_t)bk * 32 + tid) * 32;
        float o1 = fc1_b[bk * 32 + tid];
        #pragma unroll
        for (int i = 0; i < 15; ++i) {
            const float o0i = s_o0[i];
            const float sq  = clip127(o0i * o0i * (1.0f/524288.0f));
            const float rl  = clip127(o0i * (1.0f/64.0f));
            o1 += sq * w1[i] + rl * w1[15 + i];
        }
        const float ac1 = clip127(o1 * (1.0f/64.0f));
        float v = ac1 * fc2_w[bk * 32 + tid];
        v += __shfl_down(v, 16);
        v += __shfl_down(v, 8);
        v += __shfl_down(v, 4);
        v += __shfl_down(v, 2);
        v += __shfl_down(v, 1);
        if (tid == 0) {
            const float scalar = v + fc2_b[bk];
            const float skip   = s_o0[15] * (9600.0f / 8128.0f);
            const float p_stm  = st ? s_psqt[8 + bk] : s_psqt[bk];
            const float p_opp  = st ? s_psqt[bk]     : s_psqt[8 + bk];
            const float psqt   = (p_stm - p_opp) * 0.5f;
            out[b] = (psqt + scalar + skip) * (1.0f/16.0f);
        }
    }
}

extern "C" void kernel_launch(void* const* d_in, const int* in_sizes, int n_in,
                              void* d_out, int out_size, void* d_ws, size_t ws_size,
                              hipStream_t stream) {
    const int*   w_feats = (const int*)  d_in[0];
    const int*   b_feats = (const int*)  d_in[2];
    const int*   stm     = (const int*)  d_in[4];
    const int*   bucket  = (const int*)  d_in[5];
    const float* ft_w    = (const float*)d_in[6];
    const float* ft_bias = (const float*)d_in[7];
    const float* psqt_w  = (const float*)d_in[8];
    const float* fc0_w   = (const float*)d_in[9];
    const float* fc0_b   = (const float*)d_in[10];
    const float* fc1_w   = (const float*)d_in[11];
    const float* fc1_b   = (const float*)d_in[12];
    const float* fc2_w   = (const float*)d_in[13];
    const float* fc2_b   = (const float*)d_in[14];
    float* out = (float*)d_out;

    const int nB = in_sizes[4];

    const size_t need = FT_ELEMS;   // 23,068,672 B of int8
    if (ws_size >= need) {
        const unsigned n16 = (unsigned)(FT_ELEMS / 16);
        quant_f32_u8<<<2048, 256, 0, stream>>>((const float4*)ft_w, (uint4*)d_ws, n16);
        nnue_fwd_q8<<<nB, 256, 0, stream>>>(w_feats, b_feats, stm, bucket,
                                            (const uint4*)d_ws, ft_bias, psqt_w,
                                            fc0_w, fc0_b, fc1_w, fc1_b, fc2_w, fc2_b,
                                            out);
    } else {
        nnue_fwd_f32<<<nB, 256, 0, stream>>>(w_feats, b_feats, stm, bucket,
                                             ft_w, ft_bias, psqt_w,
                                             fc0_w, fc0_b, fc1_w, fc1_b, fc2_w, fc2_b,
                                             out);
    }
}

// Round 5
// 110.526 us; speedup vs baseline: 1.1761x; 1.1761x over previous
//
#include <hip/hip_runtime.h>

// NNUE (HalfKA) fused forward pass for MI355X.
// Round 5: wave-per-sample, barrier-free, LDS-free. int8 table in d_ws;
// whole 1KB row = one wave-load; pairing via shfl_xor(32); fc0/fc1/fc2/psqt
// all inside the wave. fp32 fallback if ws too small.

#define FEATS 32
#define FTO   1024
#define HH    512
#define FT_ELEMS (22528ULL * 1024ULL)      // int8 bytes = 23,068,672
#define QSCALE   (6.0f / 127.0f)

__device__ __forceinline__ float clip127(float x) {
    return fminf(fmaxf(x, 0.0f), 127.0f);
}

// ---------------- fp32 -> biased int8 quantize ----------------
__global__ __launch_bounds__(256) void quant_f32_u8(const float4* __restrict__ src,
                                                    uint4* __restrict__ dst,
                                                    unsigned n16) {
    unsigned i = blockIdx.x * 256 + threadIdx.x;
    const unsigned stride = gridDim.x * 256;
    const float inv = 127.0f / 6.0f;
    for (; i < n16; i += stride) {
        unsigned w[4];
        #pragma unroll
        for (int j = 0; j < 4; ++j) {
            const float4 v = src[4 * (size_t)i + j];
            const unsigned q0 = (unsigned)(__float2int_rn(fminf(fmaxf(v.x * inv, -127.f), 127.f)) + 128);
            const unsigned q1 = (unsigned)(__float2int_rn(fminf(fmaxf(v.y * inv, -127.f), 127.f)) + 128);
            const unsigned q2 = (unsigned)(__float2int_rn(fminf(fmaxf(v.z * inv, -127.f), 127.f)) + 128);
            const unsigned q3 = (unsigned)(__float2int_rn(fminf(fmaxf(v.w * inv, -127.f), 127.f)) + 128);
            w[j] = q0 | (q1 << 8) | (q2 << 16) | (q3 << 24);
        }
        dst[i] = make_uint4(w[0], w[1], w[2], w[3]);
    }
}

__device__ __forceinline__ void dec16(const uint4 v, unsigned* acc) {
    acc[0] += __builtin_amdgcn_perm(v.x, v.x, 0x0C010C00u);
    acc[1] += __builtin_amdgcn_perm(v.x, v.x, 0x0C030C02u);
    acc[2] += __builtin_amdgcn_perm(v.y, v.y, 0x0C010C00u);
    acc[3] += __builtin_amdgcn_perm(v.y, v.y, 0x0C030C02u);
    acc[4] += __builtin_amdgcn_perm(v.z, v.z, 0x0C010C00u);
    acc[5] += __builtin_amdgcn_perm(v.z, v.z, 0x0C030C02u);
    acc[6] += __builtin_amdgcn_perm(v.w, v.w, 0x0C010C00u);
    acc[7] += __builtin_amdgcn_perm(v.w, v.w, 0x0C030C02u);
}

// ---------------- main kernel: one wave per sample ----------------
// Lane l owns cols [16l, 16l+16) of the 1024-wide row (packed u16 pairs).
__global__ __launch_bounds__(256, 4) void nnue_wave_q8(
    const int*   __restrict__ w_feats,
    const int*   __restrict__ b_feats,
    const int*   __restrict__ stm,
    const int*   __restrict__ bucket,
    const char*  __restrict__ tb,        // int8 table, 1024 B per row
    const float* __restrict__ ft_bias,
    const float* __restrict__ psqt_w,
    const float* __restrict__ fc0_w,
    const float* __restrict__ fc0_b,
    const float* __restrict__ fc1_w,
    const float* __restrict__ fc1_b,
    const float* __restrict__ fc2_w,
    const float* __restrict__ fc2_b,
    float*       __restrict__ out,
    int nB)
{
    const int tid  = threadIdx.x;
    const int lane = tid & 63;
    const int wv   = tid >> 6;
    const int s    = blockIdx.x * 4 + wv;
    if (s >= nB) return;

    const int* __restrict__ wf = w_feats + s * FEATS;
    const int* __restrict__ bf = b_feats + s * FEATS;
    const size_t loff = (size_t)(lane * 16);

    // ---- gather-sum both bags: 4 batches x 16 row-loads ----
    unsigned accW[8] = {0,0,0,0,0,0,0,0};
    unsigned accB[8] = {0,0,0,0,0,0,0,0};
    {
        uint4 buf[16];
        #pragma unroll
        for (int batch = 0; batch < 4; ++batch) {
            const int* fp = ((batch < 2) ? wf : bf) + (batch & 1) * 16;
            #pragma unroll
            for (int k = 0; k < 16; ++k)
                buf[k] = *reinterpret_cast<const uint4*>(tb + ((size_t)fp[k] << 10) + loff);
            unsigned* acc = (batch < 2) ? accW : accB;
            #pragma unroll
            for (int k = 0; k < 16; ++k) dec16(buf[k], acc);
        }
    }

    // ---- psqt gather (tiny fp32 table): col j = lane&7, row-group = lane>>3 ----
    const int pj = lane & 7, rg = lane >> 3;
    float psw = 0.0f, psb = 0.0f;
    #pragma unroll
    for (int t = 0; t < 4; ++t) psw += psqt_w[(size_t)wf[t * 8 + rg] * 8 + pj];
    #pragma unroll
    for (int t = 0; t < 4; ++t) psb += psqt_w[(size_t)bf[t * 8 + rg] * 8 + pj];
    psw += __shfl_xor(psw, 8);  psb += __shfl_xor(psb, 8);
    psw += __shfl_xor(psw, 16); psb += __shfl_xor(psb, 16);
    psw += __shfl_xor(psw, 32); psb += __shfl_xor(psb, 32);
    // now every lane holds the bag-sum for col (lane&7)

    // ---- stm select + half-swap (pairing h <-> h+512 in-register) ----
    const int st = stm[s];
    unsigned as_[8], ao_[8];
    #pragma unroll
    for (int i = 0; i < 8; ++i) {
        as_[i] = st ? accB[i] : accW[i];
        ao_[i] = st ? accW[i] : accB[i];
    }
    unsigned asw[8], aosw[8];
    #pragma unroll
    for (int i = 0; i < 8; ++i) {
        asw[i]  = __shfl_xor(as_[i], 32);
        aosw[i] = __shfl_xor(ao_[i], 32);
    }
    const bool hiG  = (lane >= 32);
    const int cbase = (lane & 31) * 16;

    // ---- decode + pairwise clip-mult: lane holds ft[16*lane .. 16*lane+16) ----
    const float qs   = QSCALE;
    const float qoff = -4096.0f * QSCALE;   // 32 rows * 128 bias
    float ftv[16];
    #pragma unroll
    for (int i2 = 0; i2 < 8; ++i2) {
        const unsigned lo = hiG ? aosw[i2] : as_[i2];
        const unsigned hi = hiG ? ao_[i2]  : asw[i2];
        const float bl0 = ft_bias[cbase + 2 * i2];
        const float bl1 = ft_bias[cbase + 2 * i2 + 1];
        const float bh0 = ft_bias[cbase + HH + 2 * i2];
        const float bh1 = ft_bias[cbase + HH + 2 * i2 + 1];
        const float a0 = (float)(lo & 0xFFFFu) * qs + (bl0 + qoff);
        const float a1 = (float)(lo >> 16)     * qs + (bl1 + qoff);
        const float h0 = (float)(hi & 0xFFFFu) * qs + (bh0 + qoff);
        const float h1 = (float)(hi >> 16)     * qs + (bh1 + qoff);
        ftv[2 * i2]     = clip127(a0) * clip127(h0) * (1.0f / 128.0f);
        ftv[2 * i2 + 1] = clip127(a1) * clip127(h1) * (1.0f / 128.0f);
    }

    // ---- fc0: 16 outputs; lane's slice is w0[o][16*lane .. +16) (coalesced) ----
    const int bk = bucket[s];
    const float* __restrict__ w0 = fc0_w + (size_t)bk * 16 * FTO + 16 * lane;
    float o0[16];
    #pragma unroll
    for (int o = 0; o < 16; ++o) {
        const float4* wr = reinterpret_cast<const float4*>(w0 + o * FTO);
        float pv = 0.0f;
        #pragma unroll
        for (int q = 0; q < 4; ++q) {
            const float4 w = wr[q];
            pv += ftv[4*q] * w.x + ftv[4*q+1] * w.y + ftv[4*q+2] * w.z + ftv[4*q+3] * w.w;
        }
        pv += __shfl_xor(pv, 1);
        pv += __shfl_xor(pv, 2);
        pv += __shfl_xor(pv, 4);
        pv += __shfl_xor(pv, 8);
        pv += __shfl_xor(pv, 16);
        pv += __shfl_xor(pv, 32);
        o0[o] = pv + fc0_b[bk * 16 + o];
    }

    // ---- tail: fc1 (32 outs on lanes 0..31), fc2, skip, psqt ----
    float v = 0.0f;
    if (lane < 32) {
        const float* __restrict__ w1 = fc1_w + ((size_t)bk * 32 + lane) * 32;
        float o1 = fc1_b[bk * 32 + lane];
        #pragma unroll
        for (int i = 0; i < 15; ++i) {
            const float o0i = o0[i];
            const float sq  = clip127(o0i * o0i * (1.0f/524288.0f));
            const float rl  = clip127(o0i * (1.0f/64.0f));
            o1 += sq * w1[i] + rl * w1[15 + i];
        }
        const float ac1 = clip127(o1 * (1.0f/64.0f));
        v = ac1 * fc2_w[bk * 32 + lane];
    }
    v += __shfl_xor(v, 1);
    v += __shfl_xor(v, 2);
    v += __shfl_xor(v, 4);
    v += __shfl_xor(v, 8);
    v += __shfl_xor(v, 16);
    v += __shfl_xor(v, 32);   // upper half contributes zeros

    const float pwbk = __shfl(psw, bk);
    const float pbbk = __shfl(psb, bk);

    if (lane == 0) {
        const float scalar = v + fc2_b[bk];
        const float skip   = o0[15] * (9600.0f / 8128.0f);
        const float p_stm  = st ? pbbk : pwbk;
        const float p_opp  = st ? pwbk : pbbk;
        out[s] = ((p_stm - p_opp) * 0.5f + scalar + skip) * (1.0f / 16.0f);
    }
}

// ---------------- fp32 fallback (round-1 kernel) ----------------
__global__ __launch_bounds__(256) void nnue_fwd_f32(
    const int*   __restrict__ w_feats,
    const int*   __restrict__ b_feats,
    const int*   __restrict__ stm,
    const int*   __restrict__ bucket,
    const float* __restrict__ ft_w,
    const float* __restrict__ ft_bias,
    const float* __restrict__ psqt_w,
    const float* __restrict__ fc0_w,
    const float* __restrict__ fc0_b,
    const float* __restrict__ fc1_w,
    const float* __restrict__ fc1_b,
    const float* __restrict__ fc2_w,
    const float* __restrict__ fc2_b,
    float*       __restrict__ out)
{
    const int b   = blockIdx.x;
    const int tid = threadIdx.x;

    __shared__ int   sfw[FEATS];
    __shared__ int   sfb[FEATS];
    __shared__ float s_acc[2][FTO];
    __shared__ float s_part[4][16];
    __shared__ float s_o0[16];
    __shared__ float s_psqt[16];

    if (tid < FEATS)          sfw[tid]         = w_feats[b * FEATS + tid];
    else if (tid < 2 * FEATS) sfb[tid - FEATS] = b_feats[b * FEATS + (tid - FEATS)];
    __syncthreads();

    const float4* __restrict__ ftw4 = reinterpret_cast<const float4*>(ft_w);
    const float4 bias4 = reinterpret_cast<const float4*>(ft_bias)[tid];
    float4 aw = bias4, ab = bias4;

    #pragma unroll 8
    for (int k = 0; k < FEATS; ++k) {
        const float4 rw = ftw4[(size_t)sfw[k] * 256 + tid];
        const float4 rb = ftw4[(size_t)sfb[k] * 256 + tid];
        aw.x += rw.x; aw.y += rw.y; aw.z += rw.z; aw.w += rw.w;
        ab.x += rb.x; ab.y += rb.y; ab.z += rb.z; ab.w += rb.w;
    }

    if (tid < 16) {
        const int* f = (tid < 8) ? sfw : sfb;
        const int  j = tid & 7;
        float s = 0.0f;
        #pragma unroll 4
        for (int k = 0; k < FEATS; ++k) s += psqt_w[(size_t)f[k] * 8 + j];
        s_psqt[tid] = s;
    }

    const int st = stm[b];
    const float4 astm = st ? ab : aw;
    const float4 aopp = st ? aw : ab;

    reinterpret_cast<float4*>(&s_acc[0][0])[tid] = astm;
    reinterpret_cast<float4*>(&s_acc[1][0])[tid] = aopp;
    __syncthreads();

    float4 ft4;
    if (tid < 128) {
        const float4 lo = astm;
        const float4 hi = *reinterpret_cast<const float4*>(&s_acc[0][HH + tid * 4]);
        ft4.x = clip127(lo.x) * clip127(hi.x) * (1.0f/128.0f);
        ft4.y = clip127(lo.y) * clip127(hi.y) * (1.0f/128.0f);
        ft4.z = clip127(lo.z) * clip127(hi.z) * (1.0f/128.0f);
        ft4.w = clip127(lo.w) * clip127(hi.w) * (1.0f/128.0f);
    } else {
        const float4 lo = *reinterpret_cast<const float4*>(&s_acc[1][(tid - 128) * 4]);
        const float4 hi = aopp;
        ft4.x = clip127(lo.x) * clip127(hi.x) * (1.0f/128.0f);
        ft4.y = clip127(lo.y) * clip127(hi.y) * (1.0f/128.0f);
        ft4.z = clip127(lo.z) * clip127(hi.z) * (1.0f/128.0f);
        ft4.w = clip127(lo.w) * clip127(hi.w) * (1.0f/128.0f);
    }

    const int bk = bucket[b];
    const float4* __restrict__ w0 =
        reinterpret_cast<const float4*>(fc0_w + (size_t)bk * 16 * FTO);
    float p[16];
    #pragma unroll
    for (int o = 0; o < 16; ++o) {
        const float4 w = w0[o * 256 + tid];
        p[o] = ft4.x * w.x + ft4.y * w.y + ft4.z * w.z + ft4.w * w.w;
    }
    const int lane = tid & 63;
    const int wv   = tid >> 6;
    #pragma unroll
    for (int o = 0; o < 16; ++o) {
        float v = p[o];
        v += __shfl_down(v, 32);
        v += __shfl_down(v, 16);
        v += __shfl_down(v, 8);
        v += __shfl_down(v, 4);
        v += __shfl_down(v, 2);
        v += __shfl_down(v, 1);
        if (lane == 0) s_part[wv][o] = v;
    }
    __syncthreads();
    if (tid < 16) {
        s_o0[tid] = s_part[0][tid] + s_part[1][tid] + s_part[2][tid] + s_part[3][tid]
                  + fc0_b[bk * 16 + tid];
    }
    __syncthreads();

    if (tid < 32) {
        const float* __restrict__ w1 = fc1_w + ((size_t)bk * 32 + tid) * 32;
        float o1 = fc1_b[bk * 32 + tid];
        #pragma unroll
        for (int i = 0; i < 15; ++i) {
            const float o0i = s_o0[i];
            const float sq  = clip127(o0i * o0i * (1.0f/524288.0f));
            const float rl  = clip127(o0i * (1.0f/64.0f));
            o1 += sq * w1[i] + rl * w1[15 + i];
        }
        const float ac1 = clip127(o1 * (1.0f/64.0f));
        float v = ac1 * fc2_w[bk * 32 + tid];
        v += __shfl_down(v, 16);
        v += __shfl_down(v, 8);
        v += __shfl_down(v, 4);
        v += __shfl_down(v, 2);
        v += __shfl_down(v, 1);
        if (tid == 0) {
            const float scalar = v + fc2_b[bk];
            const float skip   = s_o0[15] * (9600.0f / 8128.0f);
            const float p_stm  = st ? s_psqt[8 + bk] : s_psqt[bk];
            const float p_opp  = st ? s_psqt[bk]     : s_psqt[8 + bk];
            const float psqt   = (p_stm - p_opp) * 0.5f;
            out[b] = (psqt + scalar + skip) * (1.0f/16.0f);
        }
    }
}

extern "C" void kernel_launch(void* const* d_in, const int* in_sizes, int n_in,
                              void* d_out, int out_size, void* d_ws, size_t ws_size,
                              hipStream_t stream) {
    const int*   w_feats = (const int*)  d_in[0];
    const int*   b_feats = (const int*)  d_in[2];
    const int*   stm     = (const int*)  d_in[4];
    const int*   bucket  = (const int*)  d_in[5];
    const float* ft_w    = (const float*)d_in[6];
    const float* ft_bias = (const float*)d_in[7];
    const float* psqt_w  = (const float*)d_in[8];
    const float* fc0_w   = (const float*)d_in[9];
    const float* fc0_b   = (const float*)d_in[10];
    const float* fc1_w   = (const float*)d_in[11];
    const float* fc1_b   = (const float*)d_in[12];
    const float* fc2_w   = (const float*)d_in[13];
    const float* fc2_b   = (const float*)d_in[14];
    float* out = (float*)d_out;

    const int nB = in_sizes[4];

    const size_t need = FT_ELEMS;   // 23,068,672 B of int8
    if (ws_size >= need) {
        const unsigned n16 = (unsigned)(FT_ELEMS / 16);
        quant_f32_u8<<<2048, 256, 0, stream>>>((const float4*)ft_w, (uint4*)d_ws, n16);
        nnue_wave_q8<<<(nB + 3) / 4, 256, 0, stream>>>(w_feats, b_feats, stm, bucket,
                                                       (const char*)d_ws, ft_bias, psqt_w,
                                                       fc0_w, fc0_b, fc1_w, fc1_b, fc2_w, fc2_b,
                                                       out, nB);
    } else {
        nnue_fwd_f32<<<nB, 256, 0, stream>>>(w_feats, b_feats, stm, bucket,
                                             ft_w, ft_bias, psqt_w,
                                             fc0_w, fc0_b, fc1_w, fc1_b, fc2_w, fc2_b,
                                             out);
    }
}

// Round 6
// 91.840 us; speedup vs baseline: 1.4154x; 1.2035x over previous
//
#include <hip/hip_runtime.h>
#include <hip/hip_fp16.h>

// NNUE (HalfKA) fused forward pass for MI355X.
// Round 6: XCD-column-sharded int8 gather (K1, table slice L2-resident per
// XCD) + wave-per-sample tail (K2) with fp16 fc0 weights.
// Fallbacks: round-5 wave kernel (ws >= 23MB), round-1 fp32 (else).

#define FEATS 32
#define FTO   1024
#define HH    512
#define ROWS  22528
#define FT_ELEMS  (22528ULL * 1024ULL)     // int8 table bytes = 23,068,672
#define FC0H_BYTES (8ULL * 16 * 1024 * 2)  // 262,144
#define QSCALE   (6.0f / 127.0f)

__device__ __forceinline__ float clip127(float x) {
    return fminf(fmaxf(x, 0.0f), 127.0f);
}

__device__ __forceinline__ void dec16(const uint4 v, unsigned* acc) {
    acc[0] += __builtin_amdgcn_perm(v.x, v.x, 0x0C010C00u);
    acc[1] += __builtin_amdgcn_perm(v.x, v.x, 0x0C030C02u);
    acc[2] += __builtin_amdgcn_perm(v.y, v.y, 0x0C010C00u);
    acc[3] += __builtin_amdgcn_perm(v.y, v.y, 0x0C030C02u);
    acc[4] += __builtin_amdgcn_perm(v.z, v.z, 0x0C010C00u);
    acc[5] += __builtin_amdgcn_perm(v.z, v.z, 0x0C030C02u);
    acc[6] += __builtin_amdgcn_perm(v.w, v.w, 0x0C010C00u);
    acc[7] += __builtin_amdgcn_perm(v.w, v.w, 0x0C030C02u);
}

__device__ __forceinline__ unsigned quant16(const float4 a, const float4 b,
                                            const float4 c, const float4 d,
                                            unsigned* w) {
    const float inv = 127.0f / 6.0f;
    const float4 vs[4] = {a, b, c, d};
    #pragma unroll
    for (int j = 0; j < 4; ++j) {
        const float4 v = vs[j];
        const unsigned q0 = (unsigned)(__float2int_rn(fminf(fmaxf(v.x * inv, -127.f), 127.f)) + 128);
        const unsigned q1 = (unsigned)(__float2int_rn(fminf(fmaxf(v.y * inv, -127.f), 127.f)) + 128);
        const unsigned q2 = (unsigned)(__float2int_rn(fminf(fmaxf(v.z * inv, -127.f), 127.f)) + 128);
        const unsigned q3 = (unsigned)(__float2int_rn(fminf(fmaxf(v.w * inv, -127.f), 127.f)) + 128);
        w[j] = q0 | (q1 << 8) | (q2 << 16) | (q3 << 24);
    }
    return 0;
}

// ---------------- quantize: fp32 -> biased int8, SHARDED layout ----------------
// tbl_sh[g][row][c], g = col-group (128 cols), c in [0,128). g = blockIdx&7 so
// slice g is written (and stays warm) on XCD g.
__global__ __launch_bounds__(256) void quant_sh(const float* __restrict__ src,
                                                char* __restrict__ tbl_sh) {
    const int g      = blockIdx.x & 7;
    const int chunk  = blockIdx.x >> 3;          // [0, 704)
    const int t      = threadIdx.x;
    const int row    = chunk * 32 + (t >> 3);
    const int c16    = (t & 7) * 16;             // col offset within slice
    const float4* s4 = reinterpret_cast<const float4*>(
        src + (size_t)row * FTO + g * 128 + c16);
    unsigned w[4];
    quant16(s4[0], s4[1], s4[2], s4[3], w);
    *reinterpret_cast<uint4*>(tbl_sh + (size_t)g * (ROWS * 128)
                              + (size_t)row * 128 + c16) =
        make_uint4(w[0], w[1], w[2], w[3]);
}

// ---------------- quantize: fp32 -> biased int8, row-major (fallback) ----------
__global__ __launch_bounds__(256) void quant_f32_u8(const float4* __restrict__ src,
                                                    uint4* __restrict__ dst,
                                                    unsigned n16) {
    unsigned i = blockIdx.x * 256 + threadIdx.x;
    const unsigned stride = gridDim.x * 256;
    for (; i < n16; i += stride) {
        unsigned w[4];
        quant16(src[4*(size_t)i], src[4*(size_t)i+1], src[4*(size_t)i+2],
                src[4*(size_t)i+3], w);
        dst[i] = make_uint4(w[0], w[1], w[2], w[3]);
    }
}

// ---------------- fc0 weights fp32 -> fp16 ----------------
__global__ __launch_bounds__(256) void cvt_fc0_h(const float* __restrict__ src,
                                                 __half* __restrict__ dst, int n) {
    const int i = blockIdx.x * 256 + threadIdx.x;
    if (i < n) dst[i] = __float2half_rn(src[i]);
}

// ---------------- K1: column-sharded gather ----------------
// Block handles col-group g = blockIdx&7 on XCD g (heuristic). Wave handles 4
// samples; per sample 8 wave-loads (2 bags x 4), each load = 8 rows x 128B.
// Lane: r = lane>>3 (row in group), c = lane&7 (16-col chunk).
__global__ __launch_bounds__(256, 4) void k1_gather(
    const int*  __restrict__ w_feats,
    const int*  __restrict__ b_feats,
    const char* __restrict__ tbl_sh,
    unsigned*   __restrict__ acc_ws,
    int nB)
{
    const int tid  = threadIdx.x;
    const int lane = tid & 63;
    const int wv   = tid >> 6;
    const int g     = blockIdx.x & 7;
    const int chunk = blockIdx.x >> 3;
    const int slot  = chunk * 4 + wv;
    const int r = lane >> 3;
    const int c = lane & 7;
    const size_t gbase = (size_t)g * (ROWS * 128);

    #pragma unroll
    for (int k = 0; k < 4; ++k) {
        const int s = slot * 4 + k;
        if (s >= nB) return;

        int il;
        if (lane < 32) il = w_feats[s * FEATS + lane];
        else           il = b_feats[s * FEATS + (lane & 31)];

        uint4 buf[8];
        #pragma unroll
        for (int i = 0; i < 8; ++i) {
            const int src = ((i < 4) ? 0 : 32) + (i & 3) * 8 + r;
            const int row = __shfl(il, src);
            buf[i] = *reinterpret_cast<const uint4*>(
                tbl_sh + gbase + (size_t)row * 128 + c * 16);
        }

        unsigned aW[8] = {0,0,0,0,0,0,0,0};
        unsigned aB[8] = {0,0,0,0,0,0,0,0};
        #pragma unroll
        for (int i = 0; i < 4; ++i) dec16(buf[i], aW);
        #pragma unroll
        for (int i = 4; i < 8; ++i) dec16(buf[i], aB);

        #pragma unroll
        for (int j = 0; j < 8; ++j) {
            aW[j] += __shfl_xor(aW[j], 8);
            aW[j] += __shfl_xor(aW[j], 16);
            aW[j] += __shfl_xor(aW[j], 32);
            aB[j] += __shfl_xor(aB[j], 8);
            aB[j] += __shfl_xor(aB[j], 16);
            aB[j] += __shfl_xor(aB[j], 32);
        }

        // lanes 0-7 store bag W chunk c=lane; lanes 8-15 store bag B chunk c=lane-8
        if (lane < 8) {
            unsigned* p = acc_ws + ((size_t)(s * 2 + 0) * 64 + 8 * g + lane) * 8;
            reinterpret_cast<uint4*>(p)[0] = make_uint4(aW[0], aW[1], aW[2], aW[3]);
            reinterpret_cast<uint4*>(p)[1] = make_uint4(aW[4], aW[5], aW[6], aW[7]);
        } else if (lane < 16) {
            unsigned* p = acc_ws + ((size_t)(s * 2 + 1) * 64 + 8 * g + (lane - 8)) * 8;
            reinterpret_cast<uint4*>(p)[0] = make_uint4(aB[0], aB[1], aB[2], aB[3]);
            reinterpret_cast<uint4*>(p)[1] = make_uint4(aB[4], aB[5], aB[6], aB[7]);
        }
    }
}

// ---------------- K2: combine + pairwise + fc0(fp16) + tail ----------------
// Wave per sample; lane l owns cols [16l, 16l+16) (packed u16 pairs).
__global__ __launch_bounds__(256, 4) void k2_tail(
    const int*      __restrict__ w_feats,
    const int*      __restrict__ b_feats,
    const int*      __restrict__ stm,
    const int*      __restrict__ bucket,
    const unsigned* __restrict__ acc_ws,
    const float*    __restrict__ ft_bias,
    const float*    __restrict__ psqt_w,
    const __half*   __restrict__ fc0h,
    const float*    __restrict__ fc0_b,
    const float*    __restrict__ fc1_w,
    const float*    __restrict__ fc1_b,
    const float*    __restrict__ fc2_w,
    const float*    __restrict__ fc2_b,
    float*          __restrict__ out,
    int nB)
{
    const int tid  = threadIdx.x;
    const int lane = tid & 63;
    const int wv   = tid >> 6;
    const int s    = blockIdx.x * 4 + wv;
    if (s >= nB) return;

    const int* __restrict__ wf = w_feats + s * FEATS;
    const int* __restrict__ bf = b_feats + s * FEATS;

    // ---- read packed accumulators ----
    const uint4* pW = reinterpret_cast<const uint4*>(
        acc_ws + ((size_t)(s * 2 + 0) * 64 + lane) * 8);
    const uint4* pB = reinterpret_cast<const uint4*>(
        acc_ws + ((size_t)(s * 2 + 1) * 64 + lane) * 8);
    const uint4 w0_ = pW[0], w1_ = pW[1], b0_ = pB[0], b1_ = pB[1];
    unsigned accW[8] = {w0_.x, w0_.y, w0_.z, w0_.w, w1_.x, w1_.y, w1_.z, w1_.w};
    unsigned accB[8] = {b0_.x, b0_.y, b0_.z, b0_.w, b1_.x, b1_.y, b1_.z, b1_.w};

    // ---- psqt gather (tiny fp32 table) ----
    const int pj = lane & 7, rg = lane >> 3;
    float psw = 0.0f, psb = 0.0f;
    #pragma unroll
    for (int t = 0; t < 4; ++t) psw += psqt_w[(size_t)wf[t * 8 + rg] * 8 + pj];
    #pragma unroll
    for (int t = 0; t < 4; ++t) psb += psqt_w[(size_t)bf[t * 8 + rg] * 8 + pj];
    psw += __shfl_xor(psw, 8);  psb += __shfl_xor(psb, 8);
    psw += __shfl_xor(psw, 16); psb += __shfl_xor(psb, 16);
    psw += __shfl_xor(psw, 32); psb += __shfl_xor(psb, 32);

    // ---- stm select + half-swap pairing ----
    const int st = stm[s];
    unsigned as_[8], ao_[8];
    #pragma unroll
    for (int i = 0; i < 8; ++i) {
        as_[i] = st ? accB[i] : accW[i];
        ao_[i] = st ? accW[i] : accB[i];
    }
    unsigned asw[8], aosw[8];
    #pragma unroll
    for (int i = 0; i < 8; ++i) {
        asw[i]  = __shfl_xor(as_[i], 32);
        aosw[i] = __shfl_xor(ao_[i], 32);
    }
    const bool hiG  = (lane >= 32);
    const int cbase = (lane & 31) * 16;

    const float qs   = QSCALE;
    const float qoff = -4096.0f * QSCALE;   // 32 rows * 128 bias
    float ftv[16];
    #pragma unroll
    for (int i2 = 0; i2 < 8; ++i2) {
        const unsigned lo = hiG ? aosw[i2] : as_[i2];
        const unsigned hi = hiG ? ao_[i2]  : asw[i2];
        const float bl0 = ft_bias[cbase + 2 * i2];
        const float bl1 = ft_bias[cbase + 2 * i2 + 1];
        const float bh0 = ft_bias[cbase + HH + 2 * i2];
        const float bh1 = ft_bias[cbase + HH + 2 * i2 + 1];
        const float a0 = (float)(lo & 0xFFFFu) * qs + (bl0 + qoff);
        const float a1 = (float)(lo >> 16)     * qs + (bl1 + qoff);
        const float h0 = (float)(hi & 0xFFFFu) * qs + (bh0 + qoff);
        const float h1 = (float)(hi >> 16)     * qs + (bh1 + qoff);
        ftv[2 * i2]     = clip127(a0) * clip127(h0) * (1.0f / 128.0f);
        ftv[2 * i2 + 1] = clip127(a1) * clip127(h1) * (1.0f / 128.0f);
    }

    // ---- fc0 (fp16 weights): lane slice [16l, 16l+16), coalesced ----
    const int bk = bucket[s];
    const __half* __restrict__ w0h = fc0h + (size_t)bk * 16 * FTO + 16 * lane;
    float o0[16];
    #pragma unroll
    for (int o = 0; o < 16; ++o) {
        const uint4* wr = reinterpret_cast<const uint4*>(w0h + (size_t)o * FTO);
        const uint4 ha = wr[0], hb = wr[1];
        float pv = 0.0f;
        const __half2* h1p = reinterpret_cast<const __half2*>(&ha);
        #pragma unroll
        for (int j = 0; j < 4; ++j) {
            const float2 f = __half22float2(h1p[j]);
            pv += ftv[2 * j] * f.x + ftv[2 * j + 1] * f.y;
        }
        const __half2* h2p = reinterpret_cast<const __half2*>(&hb);
        #pragma unroll
        for (int j = 0; j < 4; ++j) {
            const float2 f = __half22float2(h2p[j]);
            pv += ftv[8 + 2 * j] * f.x + ftv[9 + 2 * j] * f.y;
        }
        pv += __shfl_xor(pv, 1);
        pv += __shfl_xor(pv, 2);
        pv += __shfl_xor(pv, 4);
        pv += __shfl_xor(pv, 8);
        pv += __shfl_xor(pv, 16);
        pv += __shfl_xor(pv, 32);
        o0[o] = pv + fc0_b[bk * 16 + o];
    }

    // ---- tail: fc1, fc2, skip, psqt ----
    float v = 0.0f;
    if (lane < 32) {
        const float* __restrict__ w1 = fc1_w + ((size_t)bk * 32 + lane) * 32;
        float o1 = fc1_b[bk * 32 + lane];
        #pragma unroll
        for (int i = 0; i < 15; ++i) {
            const float o0i = o0[i];
            const float sq  = clip127(o0i * o0i * (1.0f/524288.0f));
            const float rl  = clip127(o0i * (1.0f/64.0f));
            o1 += sq * w1[i] + rl * w1[15 + i];
        }
        const float ac1 = clip127(o1 * (1.0f/64.0f));
        v = ac1 * fc2_w[bk * 32 + lane];
    }
    v += __shfl_xor(v, 1);
    v += __shfl_xor(v, 2);
    v += __shfl_xor(v, 4);
    v += __shfl_xor(v, 8);
    v += __shfl_xor(v, 16);
    v += __shfl_xor(v, 32);

    const float pwbk = __shfl(psw, bk);
    const float pbbk = __shfl(psb, bk);

    if (lane == 0) {
        const float scalar = v + fc2_b[bk];
        const float skip   = o0[15] * (9600.0f / 8128.0f);
        const float p_stm  = st ? pbbk : pwbk;
        const float p_opp  = st ? pwbk : pbbk;
        out[s] = ((p_stm - p_opp) * 0.5f + scalar + skip) * (1.0f / 16.0f);
    }
}

// ---------------- round-5 fallback: wave-per-sample, row-major int8 ----------
__global__ __launch_bounds__(256, 4) void nnue_wave_q8(
    const int*   __restrict__ w_feats,
    const int*   __restrict__ b_feats,
    const int*   __restrict__ stm,
    const int*   __restrict__ bucket,
    const char*  __restrict__ tb,
    const float* __restrict__ ft_bias,
    const float* __restrict__ psqt_w,
    const float* __restrict__ fc0_w,
    const float* __restrict__ fc0_b,
    const float* __restrict__ fc1_w,
    const float* __restrict__ fc1_b,
    const float* __restrict__ fc2_w,
    const float* __restrict__ fc2_b,
    float*       __restrict__ out,
    int nB)
{
    const int tid  = threadIdx.x;
    const int lane = tid & 63;
    const int wv   = tid >> 6;
    const int s    = blockIdx.x * 4 + wv;
    if (s >= nB) return;

    const int* __restrict__ wf = w_feats + s * FEATS;
    const int* __restrict__ bf = b_feats + s * FEATS;
    const size_t loff = (size_t)(lane * 16);

    unsigned accW[8] = {0,0,0,0,0,0,0,0};
    unsigned accB[8] = {0,0,0,0,0,0,0,0};
    {
        uint4 buf[16];
        #pragma unroll
        for (int batch = 0; batch < 4; ++batch) {
            const int* fp = ((batch < 2) ? wf : bf) + (batch & 1) * 16;
            #pragma unroll
            for (int k = 0; k < 16; ++k)
                buf[k] = *reinterpret_cast<const uint4*>(tb + ((size_t)fp[k] << 10) + loff);
            unsigned* acc = (batch < 2) ? accW : accB;
            #pragma unroll
            for (int k = 0; k < 16; ++k) dec16(buf[k], acc);
        }
    }

    const int pj = lane & 7, rg = lane >> 3;
    float psw = 0.0f, psb = 0.0f;
    #pragma unroll
    for (int t = 0; t < 4; ++t) psw += psqt_w[(size_t)wf[t * 8 + rg] * 8 + pj];
    #pragma unroll
    for (int t = 0; t < 4; ++t) psb += psqt_w[(size_t)bf[t * 8 + rg] * 8 + pj];
    psw += __shfl_xor(psw, 8);  psb += __shfl_xor(psb, 8);
    psw += __shfl_xor(psw, 16); psb += __shfl_xor(psb, 16);
    psw += __shfl_xor(psw, 32); psb += __shfl_xor(psb, 32);

    const int st = stm[s];
    unsigned as_[8], ao_[8];
    #pragma unroll
    for (int i = 0; i < 8; ++i) {
        as_[i] = st ? accB[i] : accW[i];
        ao_[i] = st ? accW[i] : accB[i];
    }
    unsigned asw[8], aosw[8];
    #pragma unroll
    for (int i = 0; i < 8; ++i) {
        asw[i]  = __shfl_xor(as_[i], 32);
        aosw[i] = __shfl_xor(ao_[i], 32);
    }
    const bool hiG  = (lane >= 32);
    const int cbase = (lane & 31) * 16;

    const float qs   = QSCALE;
    const float qoff = -4096.0f * QSCALE;
    float ftv[16];
    #pragma unroll
    for (int i2 = 0; i2 < 8; ++i2) {
        const unsigned lo = hiG ? aosw[i2] : as_[i2];
        const unsigned hi = hiG ? ao_[i2]  : asw[i2];
        const float bl0 = ft_bias[cbase + 2 * i2];
        const float bl1 = ft_bias[cbase + 2 * i2 + 1];
        const float bh0 = ft_bias[cbase + HH + 2 * i2];
        const float bh1 = ft_bias[cbase + HH + 2 * i2 + 1];
        const float a0 = (float)(lo & 0xFFFFu) * qs + (bl0 + qoff);
        const float a1 = (float)(lo >> 16)     * qs + (bl1 + qoff);
        const float h0 = (float)(hi & 0xFFFFu) * qs + (bh0 + qoff);
        const float h1 = (float)(hi >> 16)     * qs + (bh1 + qoff);
        ftv[2 * i2]     = clip127(a0) * clip127(h0) * (1.0f / 128.0f);
        ftv[2 * i2 + 1] = clip127(a1) * clip127(h1) * (1.0f / 128.0f);
    }

    const int bk = bucket[s];
    const float* __restrict__ w0 = fc0_w + (size_t)bk * 16 * FTO + 16 * lane;
    float o0[16];
    #pragma unroll
    for (int o = 0; o < 16; ++o) {
        const float4* wr = reinterpret_cast<const float4*>(w0 + o * FTO);
        float pv = 0.0f;
        #pragma unroll
        for (int q = 0; q < 4; ++q) {
            const float4 w = wr[q];
            pv += ftv[4*q] * w.x + ftv[4*q+1] * w.y + ftv[4*q+2] * w.z + ftv[4*q+3] * w.w;
        }
        pv += __shfl_xor(pv, 1);
        pv += __shfl_xor(pv, 2);
        pv += __shfl_xor(pv, 4);
        pv += __shfl_xor(pv, 8);
        pv += __shfl_xor(pv, 16);
        pv += __shfl_xor(pv, 32);
        o0[o] = pv + fc0_b[bk * 16 + o];
    }

    float v = 0.0f;
    if (lane < 32) {
        const float* __restrict__ w1 = fc1_w + ((size_t)bk * 32 + lane) * 32;
        float o1 = fc1_b[bk * 32 + lane];
        #pragma unroll
        for (int i = 0; i < 15; ++i) {
            const float o0i = o0[i];
            const float sq  = clip127(o0i * o0i * (1.0f/524288.0f));
            const float rl  = clip127(o0i * (1.0f/64.0f));
            o1 += sq * w1[i] + rl * w1[15 + i];
        }
        const float ac1 = clip127(o1 * (1.0f/64.0f));
        v = ac1 * fc2_w[bk * 32 + lane];
    }
    v += __shfl_xor(v, 1);
    v += __shfl_xor(v, 2);
    v += __shfl_xor(v, 4);
    v += __shfl_xor(v, 8);
    v += __shfl_xor(v, 16);
    v += __shfl_xor(v, 32);

    const float pwbk = __shfl(psw, bk);
    const float pbbk = __shfl(psb, bk);

    if (lane == 0) {
        const float scalar = v + fc2_b[bk];
        const float skip   = o0[15] * (9600.0f / 8128.0f);
        const float p_stm  = st ? pbbk : pwbk;
        const float p_opp  = st ? pwbk : pbbk;
        out[s] = ((p_stm - p_opp) * 0.5f + scalar + skip) * (1.0f / 16.0f);
    }
}

extern "C" void kernel_launch(void* const* d_in, const int* in_sizes, int n_in,
                              void* d_out, int out_size, void* d_ws, size_t ws_size,
                              hipStream_t stream) {
    const int*   w_feats = (const int*)  d_in[0];
    const int*   b_feats = (const int*)  d_in[2];
    const int*   stm     = (const int*)  d_in[4];
    const int*   bucket  = (const int*)  d_in[5];
    const float* ft_w    = (const float*)d_in[6];
    const float* ft_bias = (const float*)d_in[7];
    const float* psqt_w  = (const float*)d_in[8];
    const float* fc0_w   = (const float*)d_in[9];
    const float* fc0_b   = (const float*)d_in[10];
    const float* fc1_w   = (const float*)d_in[11];
    const float* fc1_b   = (const float*)d_in[12];
    const float* fc2_w   = (const float*)d_in[13];
    const float* fc2_b   = (const float*)d_in[14];
    float* out = (float*)d_out;

    const int nB = in_sizes[4];

    const size_t acc_bytes = (size_t)nB * 2 * 64 * 8 * 4;      // 4 KB/sample
    const size_t need_shard = FT_ELEMS + acc_bytes + FC0H_BYTES;

    if (ws_size >= need_shard) {
        char*     tbl_sh = (char*)d_ws;
        unsigned* acc_ws = (unsigned*)((char*)d_ws + FT_ELEMS);
        __half*   fc0h   = (__half*)((char*)d_ws + FT_ELEMS + acc_bytes);

        quant_sh<<<8 * (ROWS / 32), 256, 0, stream>>>(ft_w, tbl_sh);
        cvt_fc0_h<<<(8 * 16 * 1024 + 255) / 256, 256, 0, stream>>>(
            fc0_w, fc0h, 8 * 16 * 1024);
        k1_gather<<<8 * ((nB + 15) / 16), 256, 0, stream>>>(
            w_feats, b_feats, tbl_sh, acc_ws, nB);
        k2_tail<<<(nB + 3) / 4, 256, 0, stream>>>(
            w_feats, b_feats, stm, bucket, acc_ws, ft_bias, psqt_w,
            fc0h, fc0_b, fc1_w, fc1_b, fc2_w, fc2_b, out, nB);
    } else if (ws_size >= FT_ELEMS) {
        const unsigned n16 = (unsigned)(FT_ELEMS / 16);
        quant_f32_u8<<<2048, 256, 0, stream>>>((const float4*)ft_w, (uint4*)d_ws, n16);
        nnue_wave_q8<<<(nB + 3) / 4, 256, 0, stream>>>(
            w_feats, b_feats, stm, bucket, (const char*)d_ws, ft_bias, psqt_w,
            fc0_w, fc0_b, fc1_w, fc1_b, fc2_w, fc2_b, out, nB);
    }
}